// Round 3
// baseline (954.779 us; speedup 1.0000x reference)
//
#include <hip/hip_runtime.h>
#include <math.h>

// ---------------- CSR build ----------------

__global__ __launch_bounds__(256) void hist_k(const int* __restrict__ dst, int* __restrict__ cnt, int E){
  int e = blockIdx.x*256 + threadIdx.x;
  if (e < E) atomicAdd(&cnt[dst[e]], 1);
}

__global__ __launch_bounds__(256) void blocksum_k(const int* __restrict__ cnt, int* __restrict__ bsum, int N){
  int i = blockIdx.x*256 + threadIdx.x;
  int v = (i < N) ? cnt[i] : 0;
  #pragma unroll
  for (int off = 32; off; off >>= 1) v += __shfl_down(v, off, 64);
  __shared__ int s[4];
  if ((threadIdx.x & 63) == 0) s[threadIdx.x >> 6] = v;
  __syncthreads();
  if (threadIdx.x == 0) bsum[blockIdx.x] = s[0] + s[1] + s[2] + s[3];
}

// NB <= 512
__global__ __launch_bounds__(512) void scan_small_k(const int* __restrict__ bsum, int* __restrict__ boff, int NB){
  __shared__ int s[512];
  int t = threadIdx.x;
  int v = (t < NB) ? bsum[t] : 0;
  s[t] = v; __syncthreads();
  for (int off = 1; off < 512; off <<= 1){
    int x = (t >= off) ? s[t-off] : 0;
    __syncthreads();
    s[t] += x;
    __syncthreads();
  }
  if (t < NB) boff[t] = s[t] - v;  // exclusive
}

__global__ __launch_bounds__(256) void scan_final_k(const int* __restrict__ cnt, const int* __restrict__ boff,
                                                    int* __restrict__ rowptr, int* __restrict__ cursor,
                                                    float* __restrict__ dinv, int N){
  __shared__ int s[256];
  int t = threadIdx.x;
  int i = blockIdx.x*256 + t;
  int v = (i < N) ? cnt[i] : 0;
  s[t] = v; __syncthreads();
  for (int off = 1; off < 256; off <<= 1){
    int x = (t >= off) ? s[t-off] : 0;
    __syncthreads();
    s[t] += x;
    __syncthreads();
  }
  int excl = s[t] - v + boff[blockIdx.x];
  if (i < N){
    rowptr[i] = excl;
    cursor[i] = excl;
    dinv[i]   = rsqrtf((float)v + 1.0f);
    if (i == N-1) rowptr[N] = excl + v;
  }
}

// col-only scatter (wgt recomputed in agg from dinv)
__global__ __launch_bounds__(256) void fill_k(const int* __restrict__ src, const int* __restrict__ dst,
                                              int* __restrict__ cursor, int* __restrict__ col, int E){
  int e = blockIdx.x*256 + threadIdx.x;
  if (e >= E) return;
  int s = src[e], d = dst[e];
  int pos = atomicAdd(&cursor[d], 1);
  col[pos] = s;
}

// ---------------- GEMM 128x128 tile, 8x8 micro-tile, software-pipelined ----------------
// C[M,N] = act(A[M,K] @ B[K,N] + bias). Requires N%128==0, K%16==0.

template<int ACT>
__global__ __launch_bounds__(256) void gemm128_k(const float* __restrict__ A, const float* __restrict__ B,
                                                 const float* __restrict__ bias, float* __restrict__ C,
                                                 int M, int N, int K){
  __shared__ float As[16][132];
  __shared__ float Bs[16][132];
  const int tid = threadIdx.x;
  const int m0 = blockIdx.x * 128, n0 = blockIdx.y * 128;
  const int ty = tid >> 4, tx = tid & 15;          // compute coords
  const int sar = tid >> 1, sak = (tid & 1) * 8;   // A staging: row, k-offset
  const int sbk = tid >> 4, sbn = (tid & 15) * 8;  // B staging: k-row, col-offset
  int arow = m0 + sar; if (arow >= M) arow = M - 1;

  float acc[8][8];
  #pragma unroll
  for (int i = 0; i < 8; ++i)
    #pragma unroll
    for (int j = 0; j < 8; ++j) acc[i][j] = 0.f;

  // prologue load
  float4 a0 = *(const float4*)&A[(size_t)arow*K + 0 + sak];
  float4 a1 = *(const float4*)&A[(size_t)arow*K + 0 + sak + 4];
  float4 b0 = *(const float4*)&B[(size_t)(0+sbk)*N + n0 + sbn];
  float4 b1 = *(const float4*)&B[(size_t)(0+sbk)*N + n0 + sbn + 4];

  for (int k0 = 0; k0 < K; k0 += 16){
    __syncthreads();  // previous iteration's LDS reads complete before overwrite
    As[sak+0][sar]=a0.x; As[sak+1][sar]=a0.y; As[sak+2][sar]=a0.z; As[sak+3][sar]=a0.w;
    As[sak+4][sar]=a1.x; As[sak+5][sar]=a1.y; As[sak+6][sar]=a1.z; As[sak+7][sar]=a1.w;
    *(float4*)&Bs[sbk][sbn]   = b0;
    *(float4*)&Bs[sbk][sbn+4] = b1;
    __syncthreads();
    if (k0 + 16 < K){  // issue next tile's loads; latency hides under compute
      a0 = *(const float4*)&A[(size_t)arow*K + (k0+16) + sak];
      a1 = *(const float4*)&A[(size_t)arow*K + (k0+16) + sak + 4];
      b0 = *(const float4*)&B[(size_t)(k0+16+sbk)*N + n0 + sbn];
      b1 = *(const float4*)&B[(size_t)(k0+16+sbk)*N + n0 + sbn + 4];
    }
    #pragma unroll
    for (int kk = 0; kk < 16; ++kk){
      const float4 av0 = *(const float4*)&As[kk][ty*4];
      const float4 av1 = *(const float4*)&As[kk][64 + ty*4];
      const float4 bv0 = *(const float4*)&Bs[kk][tx*4];
      const float4 bv1 = *(const float4*)&Bs[kk][64 + tx*4];
      const float a[8] = {av0.x,av0.y,av0.z,av0.w,av1.x,av1.y,av1.z,av1.w};
      const float b[8] = {bv0.x,bv0.y,bv0.z,bv0.w,bv1.x,bv1.y,bv1.z,bv1.w};
      #pragma unroll
      for (int i = 0; i < 8; ++i)
        #pragma unroll
        for (int j = 0; j < 8; ++j)
          acc[i][j] += a[i]*b[j];
    }
  }

  float bl[8] = {0,0,0,0,0,0,0,0};
  if (bias){
    const float4 x0 = *(const float4*)&bias[n0 + tx*4];
    const float4 x1 = *(const float4*)&bias[n0 + 64 + tx*4];
    bl[0]=x0.x; bl[1]=x0.y; bl[2]=x0.z; bl[3]=x0.w;
    bl[4]=x1.x; bl[5]=x1.y; bl[6]=x1.z; bl[7]=x1.w;
  }
  #pragma unroll
  for (int i = 0; i < 8; ++i){
    int r = m0 + (i>>2)*64 + ty*4 + (i&3);
    if (r < M){
      float4 o0, o1;
      o0.x = acc[i][0]+bl[0]; o0.y = acc[i][1]+bl[1]; o0.z = acc[i][2]+bl[2]; o0.w = acc[i][3]+bl[3];
      o1.x = acc[i][4]+bl[4]; o1.y = acc[i][5]+bl[5]; o1.z = acc[i][6]+bl[6]; o1.w = acc[i][7]+bl[7];
      if (ACT == 1){
        o0.x=fmaxf(o0.x,0.f); o0.y=fmaxf(o0.y,0.f); o0.z=fmaxf(o0.z,0.f); o0.w=fmaxf(o0.w,0.f);
        o1.x=fmaxf(o1.x,0.f); o1.y=fmaxf(o1.y,0.f); o1.z=fmaxf(o1.z,0.f); o1.w=fmaxf(o1.w,0.f);
      }
      *(float4*)&C[(size_t)r*N + n0 + tx*4]      = o0;
      *(float4*)&C[(size_t)r*N + n0 + 64 + tx*4] = o1;
    }
  }
}

// ---------------- GEMM 64x64 (small head GEMMs) ----------------

template<int ACT>
__global__ __launch_bounds__(256) void gemm_k(const float* __restrict__ A, const float* __restrict__ B,
                                              const float* __restrict__ bias, float* __restrict__ C,
                                              int M, int N, int K){
  __shared__ float As[16][68];
  __shared__ float Bs[16][68];
  int tid = threadIdx.x;
  int m0 = blockIdx.x * 64, n0 = blockIdx.y * 64;
  int ty = tid >> 4, tx = tid & 15;
  int lm = tid >> 2, lkq = tid & 3;
  int lk = tid >> 4, ln4 = tid & 15;
  int arow = m0 + lm; if (arow >= M) arow = M - 1;

  float acc[4][4] = {{0.f}};

  for (int k0 = 0; k0 < K; k0 += 16){
    float4 av = *(const float4*)&A[(size_t)arow*K + k0 + lkq*4];
    float4 bv = *(const float4*)&B[(size_t)(k0+lk)*N + n0 + ln4*4];
    As[lkq*4+0][lm] = av.x; As[lkq*4+1][lm] = av.y; As[lkq*4+2][lm] = av.z; As[lkq*4+3][lm] = av.w;
    *(float4*)&Bs[lk][ln4*4] = bv;
    __syncthreads();
    #pragma unroll
    for (int kk = 0; kk < 16; ++kk){
      const float4 a = *(const float4*)&As[kk][ty*4];
      const float4 b = *(const float4*)&Bs[kk][tx*4];
      acc[0][0] += a.x*b.x; acc[0][1] += a.x*b.y; acc[0][2] += a.x*b.z; acc[0][3] += a.x*b.w;
      acc[1][0] += a.y*b.x; acc[1][1] += a.y*b.y; acc[1][2] += a.y*b.z; acc[1][3] += a.y*b.w;
      acc[2][0] += a.z*b.x; acc[2][1] += a.z*b.y; acc[2][2] += a.z*b.z; acc[2][3] += a.z*b.w;
      acc[3][0] += a.w*b.x; acc[3][1] += a.w*b.y; acc[3][2] += a.w*b.z; acc[3][3] += a.w*b.w;
    }
    __syncthreads();
  }

  float bv0 = 0.f, bv1 = 0.f, bv2 = 0.f, bv3 = 0.f;
  if (bias){
    const float4 b4 = *(const float4*)&bias[n0 + tx*4];
    bv0 = b4.x; bv1 = b4.y; bv2 = b4.z; bv3 = b4.w;
  }
  #pragma unroll
  for (int i = 0; i < 4; ++i){
    int r = m0 + ty*4 + i;
    if (r < M){
      float4 o;
      o.x = acc[i][0] + bv0; o.y = acc[i][1] + bv1; o.z = acc[i][2] + bv2; o.w = acc[i][3] + bv3;
      if (ACT == 1){ o.x = fmaxf(o.x,0.f); o.y = fmaxf(o.y,0.f); o.z = fmaxf(o.z,0.f); o.w = fmaxf(o.w,0.f); }
      *(float4*)&C[(size_t)r*N + n0 + tx*4] = o;
    }
  }
}

// ---------------- GCN aggregation + BN + ReLU ----------------
// One wave per node; two 32-lane halves own alternate edges (float4/lane),
// edge loop unrolled 4x per half -> 8 row-loads in flight per wave.
// Edge weight dinv[s]*dinv[n]: dinv[n] factored out of the sum.

__global__ __launch_bounds__(256) void agg_k(const float* __restrict__ hw, float* __restrict__ hout,
                                             const int* __restrict__ rowptr, const int* __restrict__ col,
                                             const float* __restrict__ dinv,
                                             const float* __restrict__ bgnn, const float* __restrict__ gamma,
                                             const float* __restrict__ beta, const float* __restrict__ mean,
                                             const float* __restrict__ var, int N){
  int n = (blockIdx.x * blockDim.x + threadIdx.x) >> 6;
  if (n >= N) return;
  int lane = threadIdx.x & 63;
  int half = lane >> 5;
  int sl   = lane & 31;
  int f    = sl * 4;
  int beg = rowptr[n], end = rowptr[n+1];

  float4 A0 = make_float4(0.f,0.f,0.f,0.f);
  float4 A1 = make_float4(0.f,0.f,0.f,0.f);
  float4 A2 = make_float4(0.f,0.f,0.f,0.f);
  float4 A3 = make_float4(0.f,0.f,0.f,0.f);

  int j = beg + half;
  for (; j + 6 < end; j += 8){
    int s0 = col[j], s1 = col[j+2], s2 = col[j+4], s3 = col[j+6];
    float w0 = dinv[s0], w1 = dinv[s1], w2 = dinv[s2], w3 = dinv[s3];
    const float4 v0 = *(const float4*)&hw[(size_t)s0*128 + f];
    const float4 v1 = *(const float4*)&hw[(size_t)s1*128 + f];
    const float4 v2 = *(const float4*)&hw[(size_t)s2*128 + f];
    const float4 v3 = *(const float4*)&hw[(size_t)s3*128 + f];
    A0.x += w0*v0.x; A0.y += w0*v0.y; A0.z += w0*v0.z; A0.w += w0*v0.w;
    A1.x += w1*v1.x; A1.y += w1*v1.y; A1.z += w1*v1.z; A1.w += w1*v1.w;
    A2.x += w2*v2.x; A2.y += w2*v2.y; A2.z += w2*v2.z; A2.w += w2*v2.w;
    A3.x += w3*v3.x; A3.y += w3*v3.y; A3.z += w3*v3.z; A3.w += w3*v3.w;
  }
  for (; j < end; j += 2){
    int s0 = col[j]; float w0 = dinv[s0];
    const float4 v0 = *(const float4*)&hw[(size_t)s0*128 + f];
    A0.x += w0*v0.x; A0.y += w0*v0.y; A0.z += w0*v0.z; A0.w += w0*v0.w;
  }
  A0.x += A1.x + A2.x + A3.x;
  A0.y += A1.y + A2.y + A3.y;
  A0.z += A1.z + A2.z + A3.z;
  A0.w += A1.w + A2.w + A3.w;

  // combine the two halves (lane ^ 32)
  A0.x += __shfl_xor(A0.x, 32, 64);
  A0.y += __shfl_xor(A0.y, 32, 64);
  A0.z += __shfl_xor(A0.z, 32, 64);
  A0.w += __shfl_xor(A0.w, 32, 64);

  if (half == 0){
    float di = dinv[n], sw = di * di;
    const float4 hv = *(const float4*)&hw[(size_t)n*128 + f];
    const float4 bg = *(const float4*)&bgnn[f];
    const float4 gm = *(const float4*)&gamma[f];
    const float4 bt = *(const float4*)&beta[f];
    const float4 mn = *(const float4*)&mean[f];
    const float4 vr = *(const float4*)&var[f];
    float4 o;
    o.x = (di*A0.x + sw*hv.x + bg.x - mn.x) * (gm.x * rsqrtf(vr.x + 1e-5f)) + bt.x;
    o.y = (di*A0.y + sw*hv.y + bg.y - mn.y) * (gm.y * rsqrtf(vr.y + 1e-5f)) + bt.y;
    o.z = (di*A0.z + sw*hv.z + bg.z - mn.z) * (gm.z * rsqrtf(vr.z + 1e-5f)) + bt.z;
    o.w = (di*A0.w + sw*hv.w + bg.w - mn.w) * (gm.w * rsqrtf(vr.w + 1e-5f)) + bt.w;
    o.x = fmaxf(o.x, 0.f); o.y = fmaxf(o.y, 0.f); o.z = fmaxf(o.z, 0.f); o.w = fmaxf(o.w, 0.f);
    *(float4*)&hout[(size_t)n*128 + f] = o;
  }
}

// ---------------- user gather, nlp-bias precompute, head ----------------

__global__ __launch_bounds__(256) void gather_k(const float* __restrict__ h, const int* __restrict__ uidx,
                                                float* __restrict__ uh, int B){
  int g = blockIdx.x*256 + threadIdx.x;
  if (g >= B*128) return;
  int i = g >> 7, f = g & 127;
  uh[g] = h[(size_t)uidx[i]*128 + f];
}

__global__ __launch_bounds__(256) void initc1_k(const float* __restrict__ b1, float* __restrict__ c1){
  c1[threadIdx.x] = b1[threadIdx.x];
}

__global__ __launch_bounds__(256) void c1acc_k(const float* __restrict__ nlp, const float* __restrict__ W1,
                                               float* __restrict__ c1, int NLP){
  int b = blockIdx.x;
  int c  = (b & 3) * 64 + (threadIdx.x & 63);
  int dq = threadIdx.x >> 6;
  int d0 = (b >> 2) * 99;
  float acc = 0.f;
  for (int d = d0 + dq; d < d0 + 99 && d < NLP; d += 4)
    acc += nlp[d] * W1[(size_t)(64 + d) * 256 + c];
  __shared__ float s[256];
  s[threadIdx.x] = acc; __syncthreads();
  if (dq == 0){
    float t = s[threadIdx.x] + s[threadIdx.x + 64] + s[threadIdx.x + 128] + s[threadIdx.x + 192];
    atomicAdd(&c1[c], t);
  }
}

__global__ __launch_bounds__(256) void head_k(const float* __restrict__ z2, const float* __restrict__ W3,
                                              const float* __restrict__ b3, float* __restrict__ out, int B){
  int gid = blockIdx.x * blockDim.x + threadIdx.x;
  int u = gid >> 6, l = gid & 63;
  if (u >= B) return;
  float v = z2[(size_t)u*128 + l] * W3[l] + z2[(size_t)u*128 + 64 + l] * W3[64 + l];
  #pragma unroll
  for (int off = 32; off; off >>= 1) v += __shfl_down(v, off, 64);
  if (l == 0) out[u] = 1.f / (1.f + expf(-(v + b3[0])));
}

// ---------------- host ----------------

static void launch_gemm128(int act, const float* A, const float* Bm, const float* bias, float* C,
                           int M, int N, int K, hipStream_t s){
  dim3 g((M + 127) / 128, N / 128);
  if (act) hipLaunchKernelGGL((gemm128_k<1>), g, dim3(256), 0, s, A, Bm, bias, C, M, N, K);
  else     hipLaunchKernelGGL((gemm128_k<0>), g, dim3(256), 0, s, A, Bm, bias, C, M, N, K);
}

static void launch_gemm(int act, const float* A, const float* Bm, const float* bias, float* C,
                        int M, int N, int K, hipStream_t s){
  dim3 g((M + 63) / 64, N / 64);
  if (act) hipLaunchKernelGGL((gemm_k<1>), g, dim3(256), 0, s, A, Bm, bias, C, M, N, K);
  else     hipLaunchKernelGGL((gemm_k<0>), g, dim3(256), 0, s, A, Bm, bias, C, M, N, K);
}

extern "C" void kernel_launch(void* const* d_in, const int* in_sizes, int n_in,
                              void* d_out, int out_size, void* d_ws, size_t ws_size,
                              hipStream_t stream){
  const float* x     = (const float*)d_in[0];
  const float* nlp   = (const float*)d_in[1];
  const int*   eidx  = (const int*)  d_in[2];
  const int*   uidx  = (const int*)  d_in[3];
  const float* W_in  = (const float*)d_in[4];
  const float* b_in  = (const float*)d_in[5];
  const float* W_gnn = (const float*)d_in[6];
  const float* b_gnn = (const float*)d_in[7];
  const float* gam   = (const float*)d_in[8];
  const float* bet   = (const float*)d_in[9];
  const float* mean  = (const float*)d_in[10];
  const float* var   = (const float*)d_in[11];
  const float* Wproj = (const float*)d_in[12];
  const float* bproj = (const float*)d_in[13];
  const float* W1    = (const float*)d_in[14];
  const float* b1    = (const float*)d_in[15];
  const float* W2    = (const float*)d_in[16];
  const float* b2    = (const float*)d_in[17];
  const float* W3    = (const float*)d_in[18];
  const float* b3    = (const float*)d_in[19];
  float* out = (float*)d_out;

  const int N   = in_sizes[0] / 128;   // 100000
  const int E   = in_sizes[2] / 2;     // 1600000
  const int B   = in_sizes[3];         // 4096
  const int NLP = in_sizes[1];         // 786
  const int HID = 128;

  char* p = (char*)d_ws;
  auto carve = [&](size_t bytes) -> void* {
    void* q = (void*)p;
    p += (bytes + 255) & ~(size_t)255;
    return q;
  };
  int*   cnt    = (int*)  carve((size_t)N * 4);
  int*   rowptr = (int*)  carve((size_t)(N + 1) * 4);
  int*   cursor = (int*)  carve((size_t)N * 4);
  int*   bsum   = (int*)  carve(512 * 4);
  int*   boff   = (int*)  carve(512 * 4);
  float* dinv   = (float*)carve((size_t)N * 4);
  int*   col    = (int*)  carve((size_t)E * 4);
  float* h      = (float*)carve((size_t)N * HID * 4);
  float* hw     = (float*)carve((size_t)N * HID * 4);
  float* uh     = (float*)carve((size_t)B * HID * 4);
  float* embu   = (float*)carve((size_t)B * 64 * 4);
  float* z1     = (float*)carve((size_t)B * 256 * 4);
  float* z2     = (float*)carve((size_t)B * 128 * 4);
  float* c1     = (float*)carve(256 * 4);

  const int* src = eidx;
  const int* dst = eidx + E;

  const int NB = (N + 255) / 256;   // 391 (<512)

  // ---- CSR build ----
  hipMemsetAsync(cnt, 0, (size_t)N * 4, stream);
  hipLaunchKernelGGL(hist_k, dim3((E + 255) / 256), dim3(256), 0, stream, dst, cnt, E);
  hipLaunchKernelGGL(blocksum_k, dim3(NB), dim3(256), 0, stream, cnt, bsum, N);
  hipLaunchKernelGGL(scan_small_k, dim3(1), dim3(512), 0, stream, bsum, boff, NB);
  hipLaunchKernelGGL(scan_final_k, dim3(NB), dim3(256), 0, stream, cnt, boff, rowptr, cursor, dinv, N);
  hipLaunchKernelGGL(fill_k, dim3((E + 255) / 256), dim3(256), 0, stream, src, dst, cursor, col, E);

  // ---- input projection ----
  launch_gemm128(1, x, W_in, b_in, h, N, HID, 128, stream);

  // ---- 3 GCN layers ----
  for (int i = 0; i < 3; ++i){
    launch_gemm128(0, h, W_gnn + (size_t)i * 128 * 128, nullptr, hw, N, HID, 128, stream);
    hipLaunchKernelGGL(agg_k, dim3((N * 64 + 255) / 256), dim3(256), 0, stream,
                       hw, h, rowptr, col, dinv,
                       b_gnn + i * 128, gam + i * 128, bet + i * 128, mean + i * 128, var + i * 128, N);
  }

  // ---- user head ----
  hipLaunchKernelGGL(gather_k, dim3((B * 128 + 255) / 256), dim3(256), 0, stream, h, uidx, uh, B);
  hipLaunchKernelGGL(initc1_k, dim3(1), dim3(256), 0, stream, b1, c1);
  hipLaunchKernelGGL(c1acc_k, dim3(32), dim3(256), 0, stream, nlp, W1, c1, NLP);

  launch_gemm(0, uh, Wproj, bproj, embu, B, 64, 128, stream);
  launch_gemm(1, embu, W1, c1, z1, B, 256, 64, stream);
  launch_gemm(1, z1, W2, b2, z2, B, 128, 256, stream);
  hipLaunchKernelGGL(head_k, dim3((B * 64 + 255) / 256), dim3(256), 0, stream, z2, W3, b3, out, B);
}

// Round 6
// 698.140 us; speedup vs baseline: 1.3676x; 1.3676x over previous
//
#include <hip/hip_runtime.h>
#include <math.h>

typedef _Float16 half4 __attribute__((ext_vector_type(4)));

// ---------------- CSR build ----------------

// histogram + per-edge rank (atomic result = rank within destination row)
__global__ __launch_bounds__(256) void hist_k(const int* __restrict__ dst, int* __restrict__ cnt,
                                              int* __restrict__ rank, int E){
  int e = blockIdx.x*256 + threadIdx.x;
  if (e < E) rank[e] = atomicAdd(&cnt[dst[e]], 1);
}

__global__ __launch_bounds__(256) void blocksum_k(const int* __restrict__ cnt, int* __restrict__ bsum, int N){
  int i = blockIdx.x*256 + threadIdx.x;
  int v = (i < N) ? cnt[i] : 0;
  #pragma unroll
  for (int off = 32; off; off >>= 1) v += __shfl_down(v, off, 64);
  __shared__ int s[4];
  if ((threadIdx.x & 63) == 0) s[threadIdx.x >> 6] = v;
  __syncthreads();
  if (threadIdx.x == 0) bsum[blockIdx.x] = s[0] + s[1] + s[2] + s[3];
}

// NB <= 512
__global__ __launch_bounds__(512) void scan_small_k(const int* __restrict__ bsum, int* __restrict__ boff, int NB){
  __shared__ int s[512];
  int t = threadIdx.x;
  int v = (t < NB) ? bsum[t] : 0;
  s[t] = v; __syncthreads();
  for (int off = 1; off < 512; off <<= 1){
    int x = (t >= off) ? s[t-off] : 0;
    __syncthreads();
    s[t] += x;
    __syncthreads();
  }
  if (t < NB) boff[t] = s[t] - v;  // exclusive
}

__global__ __launch_bounds__(256) void scan_final_k(const int* __restrict__ cnt, const int* __restrict__ boff,
                                                    int* __restrict__ rowptr,
                                                    float* __restrict__ dinv, int N){
  __shared__ int s[256];
  int t = threadIdx.x;
  int i = blockIdx.x*256 + t;
  int v = (i < N) ? cnt[i] : 0;
  s[t] = v; __syncthreads();
  for (int off = 1; off < 256; off <<= 1){
    int x = (t >= off) ? s[t-off] : 0;
    __syncthreads();
    s[t] += x;
    __syncthreads();
  }
  int excl = s[t] - v + boff[blockIdx.x];
  if (i < N){
    rowptr[i] = excl;
    dinv[i]   = rsqrtf((float)v + 1.0f);
    if (i == N-1) rowptr[N] = excl + v;
  }
}

// pure scatter, no atomic dependency
__global__ __launch_bounds__(256) void fill_k(const int* __restrict__ src, const int* __restrict__ dst,
                                              const int* __restrict__ rowptr, const int* __restrict__ rank,
                                              int* __restrict__ col, int E){
  int e = blockIdx.x*256 + threadIdx.x;
  if (e >= E) return;
  col[rowptr[dst[e]] + rank[e]] = src[e];
}

// ---------------- GEMM 128x128 tile, 8x8 micro-tile, software-pipelined ----------------
// C = act(A @ B + bias); SCALED=1: Ch[r,:] = (half) dinv[r]*(A@B)[r,:]  (no bias/act)

template<int ACT, int SCALED>
__global__ __launch_bounds__(256) void gemm128_k(const float* __restrict__ A, const float* __restrict__ B,
                                                 const float* __restrict__ bias, float* __restrict__ Cf,
                                                 _Float16* __restrict__ Ch, const float* __restrict__ dinv,
                                                 int M, int N, int K){
  __shared__ float As[16][132];
  __shared__ float Bs[16][132];
  const int tid = threadIdx.x;
  const int m0 = blockIdx.x * 128, n0 = blockIdx.y * 128;
  const int ty = tid >> 4, tx = tid & 15;
  const int sar = tid >> 1, sak = (tid & 1) * 8;
  const int sbk = tid >> 4, sbn = (tid & 15) * 8;
  int arow = m0 + sar; if (arow >= M) arow = M - 1;

  float acc[8][8];
  #pragma unroll
  for (int i = 0; i < 8; ++i)
    #pragma unroll
    for (int j = 0; j < 8; ++j) acc[i][j] = 0.f;

  float4 a0 = *(const float4*)&A[(size_t)arow*K + 0 + sak];
  float4 a1 = *(const float4*)&A[(size_t)arow*K + 0 + sak + 4];
  float4 b0 = *(const float4*)&B[(size_t)(0+sbk)*N + n0 + sbn];
  float4 b1 = *(const float4*)&B[(size_t)(0+sbk)*N + n0 + sbn + 4];

  for (int k0 = 0; k0 < K; k0 += 16){
    __syncthreads();
    As[sak+0][sar]=a0.x; As[sak+1][sar]=a0.y; As[sak+2][sar]=a0.z; As[sak+3][sar]=a0.w;
    As[sak+4][sar]=a1.x; As[sak+5][sar]=a1.y; As[sak+6][sar]=a1.z; As[sak+7][sar]=a1.w;
    *(float4*)&Bs[sbk][sbn]   = b0;
    *(float4*)&Bs[sbk][sbn+4] = b1;
    __syncthreads();
    if (k0 + 16 < K){
      a0 = *(const float4*)&A[(size_t)arow*K + (k0+16) + sak];
      a1 = *(const float4*)&A[(size_t)arow*K + (k0+16) + sak + 4];
      b0 = *(const float4*)&B[(size_t)(k0+16+sbk)*N + n0 + sbn];
      b1 = *(const float4*)&B[(size_t)(k0+16+sbk)*N + n0 + sbn + 4];
    }
    #pragma unroll
    for (int kk = 0; kk < 16; ++kk){
      const float4 av0 = *(const float4*)&As[kk][ty*4];
      const float4 av1 = *(const float4*)&As[kk][64 + ty*4];
      const float4 bv0 = *(const float4*)&Bs[kk][tx*4];
      const float4 bv1 = *(const float4*)&Bs[kk][64 + tx*4];
      const float a[8] = {av0.x,av0.y,av0.z,av0.w,av1.x,av1.y,av1.z,av1.w};
      const float b[8] = {bv0.x,bv0.y,bv0.z,bv0.w,bv1.x,bv1.y,bv1.z,bv1.w};
      #pragma unroll
      for (int i = 0; i < 8; ++i)
        #pragma unroll
        for (int j = 0; j < 8; ++j)
          acc[i][j] += a[i]*b[j];
    }
  }

  float bl[8] = {0,0,0,0,0,0,0,0};
  if (!SCALED && bias){
    const float4 x0 = *(const float4*)&bias[n0 + tx*4];
    const float4 x1 = *(const float4*)&bias[n0 + 64 + tx*4];
    bl[0]=x0.x; bl[1]=x0.y; bl[2]=x0.z; bl[3]=x0.w;
    bl[4]=x1.x; bl[5]=x1.y; bl[6]=x1.z; bl[7]=x1.w;
  }
  #pragma unroll
  for (int i = 0; i < 8; ++i){
    int r = m0 + (i>>2)*64 + ty*4 + (i&3);
    if (r < M){
      if (SCALED){
        float di = dinv[r];
        half4 h0, h1;
        h0[0]=(_Float16)(di*acc[i][0]); h0[1]=(_Float16)(di*acc[i][1]);
        h0[2]=(_Float16)(di*acc[i][2]); h0[3]=(_Float16)(di*acc[i][3]);
        h1[0]=(_Float16)(di*acc[i][4]); h1[1]=(_Float16)(di*acc[i][5]);
        h1[2]=(_Float16)(di*acc[i][6]); h1[3]=(_Float16)(di*acc[i][7]);
        *(half4*)&Ch[(size_t)r*N + n0 + tx*4]      = h0;
        *(half4*)&Ch[(size_t)r*N + n0 + 64 + tx*4] = h1;
      } else {
        float4 o0, o1;
        o0.x = acc[i][0]+bl[0]; o0.y = acc[i][1]+bl[1]; o0.z = acc[i][2]+bl[2]; o0.w = acc[i][3]+bl[3];
        o1.x = acc[i][4]+bl[4]; o1.y = acc[i][5]+bl[5]; o1.z = acc[i][6]+bl[6]; o1.w = acc[i][7]+bl[7];
        if (ACT == 1){
          o0.x=fmaxf(o0.x,0.f); o0.y=fmaxf(o0.y,0.f); o0.z=fmaxf(o0.z,0.f); o0.w=fmaxf(o0.w,0.f);
          o1.x=fmaxf(o1.x,0.f); o1.y=fmaxf(o1.y,0.f); o1.z=fmaxf(o1.z,0.f); o1.w=fmaxf(o1.w,0.f);
        }
        *(float4*)&Cf[(size_t)r*N + n0 + tx*4]      = o0;
        *(float4*)&Cf[(size_t)r*N + n0 + 64 + tx*4] = o1;
      }
    }
  }
}

// ---------------- GEMM 64x64 (small head GEMMs) ----------------

template<int ACT>
__global__ __launch_bounds__(256) void gemm_k(const float* __restrict__ A, const float* __restrict__ B,
                                              const float* __restrict__ bias, float* __restrict__ C,
                                              int M, int N, int K){
  __shared__ float As[16][68];
  __shared__ float Bs[16][68];
  int tid = threadIdx.x;
  int m0 = blockIdx.x * 64, n0 = blockIdx.y * 64;
  int ty = tid >> 4, tx = tid & 15;
  int lm = tid >> 2, lkq = tid & 3;
  int lk = tid >> 4, ln4 = tid & 15;
  int arow = m0 + lm; if (arow >= M) arow = M - 1;

  float acc[4][4] = {{0.f}};

  for (int k0 = 0; k0 < K; k0 += 16){
    float4 av = *(const float4*)&A[(size_t)arow*K + k0 + lkq*4];
    float4 bv = *(const float4*)&B[(size_t)(k0+lk)*N + n0 + ln4*4];
    As[lkq*4+0][lm] = av.x; As[lkq*4+1][lm] = av.y; As[lkq*4+2][lm] = av.z; As[lkq*4+3][lm] = av.w;
    *(float4*)&Bs[lk][ln4*4] = bv;
    __syncthreads();
    #pragma unroll
    for (int kk = 0; kk < 16; ++kk){
      const float4 a = *(const float4*)&As[kk][ty*4];
      const float4 b = *(const float4*)&Bs[kk][tx*4];
      acc[0][0] += a.x*b.x; acc[0][1] += a.x*b.y; acc[0][2] += a.x*b.z; acc[0][3] += a.x*b.w;
      acc[1][0] += a.y*b.x; acc[1][1] += a.y*b.y; acc[1][2] += a.y*b.z; acc[1][3] += a.y*b.w;
      acc[2][0] += a.z*b.x; acc[2][1] += a.z*b.y; acc[2][2] += a.z*b.z; acc[2][3] += a.z*b.w;
      acc[3][0] += a.w*b.x; acc[3][1] += a.w*b.y; acc[3][2] += a.w*b.z; acc[3][3] += a.w*b.w;
    }
    __syncthreads();
  }

  float bv0 = 0.f, bv1 = 0.f, bv2 = 0.f, bv3 = 0.f;
  if (bias){
    const float4 b4 = *(const float4*)&bias[n0 + tx*4];
    bv0 = b4.x; bv1 = b4.y; bv2 = b4.z; bv3 = b4.w;
  }
  #pragma unroll
  for (int i = 0; i < 4; ++i){
    int r = m0 + ty*4 + i;
    if (r < M){
      float4 o;
      o.x = acc[i][0] + bv0; o.y = acc[i][1] + bv1; o.z = acc[i][2] + bv2; o.w = acc[i][3] + bv3;
      if (ACT == 1){ o.x = fmaxf(o.x,0.f); o.y = fmaxf(o.y,0.f); o.z = fmaxf(o.z,0.f); o.w = fmaxf(o.w,0.f); }
      *(float4*)&C[(size_t)r*N + n0 + tx*4] = o;
    }
  }
}

// ---------------- GCN aggregation + BN + ReLU ----------------
// hws = fp16, rows pre-scaled by dinv[src].  agg = dinv[n]*(sum + hws[n]) + b, then BN+ReLU.
// One wave per node; two 32-lane halves own alternate edges; unroll 4 per half.

__global__ __launch_bounds__(256) void agg_k(const _Float16* __restrict__ hws, float* __restrict__ hout,
                                             const int* __restrict__ rowptr, const int* __restrict__ col,
                                             const float* __restrict__ dinv,
                                             const float* __restrict__ bgnn, const float* __restrict__ gamma,
                                             const float* __restrict__ beta, const float* __restrict__ mean,
                                             const float* __restrict__ var, int N){
  int n = (blockIdx.x * blockDim.x + threadIdx.x) >> 6;
  if (n >= N) return;
  int lane = threadIdx.x & 63;
  int half = lane >> 5;
  int sl   = lane & 31;
  int f    = sl * 4;
  int beg = rowptr[n], end = rowptr[n+1];

  float4 A0 = make_float4(0.f,0.f,0.f,0.f);
  float4 A1 = make_float4(0.f,0.f,0.f,0.f);
  float4 A2 = make_float4(0.f,0.f,0.f,0.f);
  float4 A3 = make_float4(0.f,0.f,0.f,0.f);

  int j = beg + half;
  for (; j + 6 < end; j += 8){
    int s0 = col[j], s1 = col[j+2], s2 = col[j+4], s3 = col[j+6];
    const half4 v0 = *(const half4*)&hws[(size_t)s0*128 + f];
    const half4 v1 = *(const half4*)&hws[(size_t)s1*128 + f];
    const half4 v2 = *(const half4*)&hws[(size_t)s2*128 + f];
    const half4 v3 = *(const half4*)&hws[(size_t)s3*128 + f];
    A0.x += (float)v0[0]; A0.y += (float)v0[1]; A0.z += (float)v0[2]; A0.w += (float)v0[3];
    A1.x += (float)v1[0]; A1.y += (float)v1[1]; A1.z += (float)v1[2]; A1.w += (float)v1[3];
    A2.x += (float)v2[0]; A2.y += (float)v2[1]; A2.z += (float)v2[2]; A2.w += (float)v2[3];
    A3.x += (float)v3[0]; A3.y += (float)v3[1]; A3.z += (float)v3[2]; A3.w += (float)v3[3];
  }
  for (; j < end; j += 2){
    int s0 = col[j];
    const half4 v0 = *(const half4*)&hws[(size_t)s0*128 + f];
    A0.x += (float)v0[0]; A0.y += (float)v0[1]; A0.z += (float)v0[2]; A0.w += (float)v0[3];
  }
  A0.x += A1.x + A2.x + A3.x;
  A0.y += A1.y + A2.y + A3.y;
  A0.z += A1.z + A2.z + A3.z;
  A0.w += A1.w + A2.w + A3.w;

  A0.x += __shfl_xor(A0.x, 32, 64);
  A0.y += __shfl_xor(A0.y, 32, 64);
  A0.z += __shfl_xor(A0.z, 32, 64);
  A0.w += __shfl_xor(A0.w, 32, 64);

  if (half == 0){
    float di = dinv[n];
    const half4 hv = *(const half4*)&hws[(size_t)n*128 + f];
    const float4 bg = *(const float4*)&bgnn[f];
    const float4 gm = *(const float4*)&gamma[f];
    const float4 bt = *(const float4*)&beta[f];
    const float4 mn = *(const float4*)&mean[f];
    const float4 vr = *(const float4*)&var[f];
    float4 o;
    o.x = (di*(A0.x + (float)hv[0]) + bg.x - mn.x) * (gm.x * rsqrtf(vr.x + 1e-5f)) + bt.x;
    o.y = (di*(A0.y + (float)hv[1]) + bg.y - mn.y) * (gm.y * rsqrtf(vr.y + 1e-5f)) + bt.y;
    o.z = (di*(A0.z + (float)hv[2]) + bg.z - mn.z) * (gm.z * rsqrtf(vr.z + 1e-5f)) + bt.z;
    o.w = (di*(A0.w + (float)hv[3]) + bg.w - mn.w) * (gm.w * rsqrtf(vr.w + 1e-5f)) + bt.w;
    o.x = fmaxf(o.x, 0.f); o.y = fmaxf(o.y, 0.f); o.z = fmaxf(o.z, 0.f); o.w = fmaxf(o.w, 0.f);
    *(float4*)&hout[(size_t)n*128 + f] = o;
  }
}

// ---------------- user gather, nlp-bias precompute, head ----------------

__global__ __launch_bounds__(256) void gather_k(const float* __restrict__ h, const int* __restrict__ uidx,
                                                float* __restrict__ uh, int B){
  int g = blockIdx.x*256 + threadIdx.x;
  if (g >= B*128) return;
  int i = g >> 7, f = g & 127;
  uh[g] = h[(size_t)uidx[i]*128 + f];
}

__global__ __launch_bounds__(256) void initc1_k(const float* __restrict__ b1, float* __restrict__ c1){
  c1[threadIdx.x] = b1[threadIdx.x];
}

__global__ __launch_bounds__(256) void c1acc_k(const float* __restrict__ nlp, const float* __restrict__ W1,
                                               float* __restrict__ c1, int NLP){
  int b = blockIdx.x;
  int c  = (b & 3) * 64 + (threadIdx.x & 63);
  int dq = threadIdx.x >> 6;
  int d0 = (b >> 2) * 99;
  float acc = 0.f;
  for (int d = d0 + dq; d < d0 + 99 && d < NLP; d += 4)
    acc += nlp[d] * W1[(size_t)(64 + d) * 256 + c];
  __shared__ float s[256];
  s[threadIdx.x] = acc; __syncthreads();
  if (dq == 0){
    float t = s[threadIdx.x] + s[threadIdx.x + 64] + s[threadIdx.x + 128] + s[threadIdx.x + 192];
    atomicAdd(&c1[c], t);
  }
}

__global__ __launch_bounds__(256) void head_k(const float* __restrict__ z2, const float* __restrict__ W3,
                                              const float* __restrict__ b3, float* __restrict__ out, int B){
  int gid = blockIdx.x * blockDim.x + threadIdx.x;
  int u = gid >> 6, l = gid & 63;
  if (u >= B) return;
  float v = z2[(size_t)u*128 + l] * W3[l] + z2[(size_t)u*128 + 64 + l] * W3[64 + l];
  #pragma unroll
  for (int off = 32; off; off >>= 1) v += __shfl_down(v, off, 64);
  if (l == 0) out[u] = 1.f / (1.f + expf(-(v + b3[0])));
}

// ---------------- host ----------------

static void launch_gemm(int act, const float* A, const float* Bm, const float* bias, float* C,
                        int M, int N, int K, hipStream_t s){
  dim3 g((M + 63) / 64, N / 64);
  if (act) hipLaunchKernelGGL((gemm_k<1>), g, dim3(256), 0, s, A, Bm, bias, C, M, N, K);
  else     hipLaunchKernelGGL((gemm_k<0>), g, dim3(256), 0, s, A, Bm, bias, C, M, N, K);
}

extern "C" void kernel_launch(void* const* d_in, const int* in_sizes, int n_in,
                              void* d_out, int out_size, void* d_ws, size_t ws_size,
                              hipStream_t stream){
  const float* x     = (const float*)d_in[0];
  const float* nlp   = (const float*)d_in[1];
  const int*   eidx  = (const int*)  d_in[2];
  const int*   uidx  = (const int*)  d_in[3];
  const float* W_in  = (const float*)d_in[4];
  const float* b_in  = (const float*)d_in[5];
  const float* W_gnn = (const float*)d_in[6];
  const float* b_gnn = (const float*)d_in[7];
  const float* gam   = (const float*)d_in[8];
  const float* bet   = (const float*)d_in[9];
  const float* mean  = (const float*)d_in[10];
  const float* var   = (const float*)d_in[11];
  const float* Wproj = (const float*)d_in[12];
  const float* bproj = (const float*)d_in[13];
  const float* W1    = (const float*)d_in[14];
  const float* b1    = (const float*)d_in[15];
  const float* W2    = (const float*)d_in[16];
  const float* b2    = (const float*)d_in[17];
  const float* W3    = (const float*)d_in[18];
  const float* b3    = (const float*)d_in[19];
  float* out = (float*)d_out;

  const int N   = in_sizes[0] / 128;   // 100000
  const int E   = in_sizes[2] / 2;     // 1600000
  const int B   = in_sizes[3];         // 4096
  const int NLP = in_sizes[1];         // 786
  const int HID = 128;

  char* p = (char*)d_ws;
  auto carve = [&](size_t bytes) -> void* {
    void* q = (void*)p;
    p += (bytes + 255) & ~(size_t)255;
    return q;
  };
  int*      cnt    = (int*)     carve((size_t)N * 4);
  int*      rowptr = (int*)     carve((size_t)(N + 1) * 4);
  int*      rank   = (int*)     carve((size_t)E * 4);
  int*      bsum   = (int*)     carve(512 * 4);
  int*      boff   = (int*)     carve(512 * 4);
  float*    dinv   = (float*)   carve((size_t)N * 4);
  int*      col    = (int*)     carve((size_t)E * 4);
  float*    h      = (float*)   carve((size_t)N * HID * 4);
  _Float16* hws    = (_Float16*)carve((size_t)N * HID * 2);
  float*    uh     = (float*)   carve((size_t)B * HID * 4);
  float*    embu   = (float*)   carve((size_t)B * 64 * 4);
  float*    z1     = (float*)   carve((size_t)B * 256 * 4);
  float*    z2     = (float*)   carve((size_t)B * 128 * 4);
  float*    c1     = (float*)   carve(256 * 4);

  const int* src = eidx;
  const int* dst = eidx + E;

  const int NB = (N + 255) / 256;   // 391 (<512)

  // ---- CSR build ----
  hipMemsetAsync(cnt, 0, (size_t)N * 4, stream);
  hipLaunchKernelGGL(hist_k, dim3((E + 255) / 256), dim3(256), 0, stream, dst, cnt, rank, E);
  hipLaunchKernelGGL(blocksum_k, dim3(NB), dim3(256), 0, stream, cnt, bsum, N);
  hipLaunchKernelGGL(scan_small_k, dim3(1), dim3(512), 0, stream, bsum, boff, NB);
  hipLaunchKernelGGL(scan_final_k, dim3(NB), dim3(256), 0, stream, cnt, boff, rowptr, dinv, N);
  hipLaunchKernelGGL(fill_k, dim3((E + 255) / 256), dim3(256), 0, stream, src, dst, rowptr, rank, col, E);

  // ---- input projection (fp32 out) ----
  {
    dim3 g((N + 127) / 128, HID / 128);
    hipLaunchKernelGGL((gemm128_k<1,0>), g, dim3(256), 0, stream,
                       x, W_in, b_in, h, (_Float16*)nullptr, (const float*)nullptr, N, HID, 128);
  }

  // ---- 3 GCN layers: gemm (scaled fp16 out) + agg ----
  for (int i = 0; i < 3; ++i){
    dim3 g((N + 127) / 128, HID / 128);
    hipLaunchKernelGGL((gemm128_k<0,1>), g, dim3(256), 0, stream,
                       h, W_gnn + (size_t)i * 128 * 128, (const float*)nullptr,
                       (float*)nullptr, hws, dinv, N, HID, 128);
    hipLaunchKernelGGL(agg_k, dim3((N * 64 + 255) / 256), dim3(256), 0, stream,
                       hws, h, rowptr, col, dinv,
                       b_gnn + i * 128, gam + i * 128, bet + i * 128, mean + i * 128, var + i * 128, N);
  }

  // ---- user head ----
  hipLaunchKernelGGL(gather_k, dim3((B * 128 + 255) / 256), dim3(256), 0, stream, h, uidx, uh, B);
  hipLaunchKernelGGL(initc1_k, dim3(1), dim3(256), 0, stream, b1, c1);
  hipLaunchKernelGGL(c1acc_k, dim3(32), dim3(256), 0, stream, nlp, W1, c1, NLP);

  launch_gemm(0, uh, Wproj, bproj, embu, B, 64, 128, stream);
  launch_gemm(1, embu, W1, c1, z1, B, 256, 64, stream);
  launch_gemm(1, z1, W2, b2, z2, B, 128, 256, stream);
  hipLaunchKernelGGL(head_k, dim3((B * 64 + 255) / 256), dim3(256), 0, stream, z2, W3, b3, out, B);
}

// Round 7
// 567.496 us; speedup vs baseline: 1.6824x; 1.2302x over previous
//
#include <hip/hip_runtime.h>
#include <math.h>

typedef _Float16 half8_t __attribute__((ext_vector_type(8)));
typedef _Float16 half4_t __attribute__((ext_vector_type(4)));
typedef float    f32x4_t __attribute__((ext_vector_type(4)));

// ---------------- CSR build ----------------

__global__ __launch_bounds__(256) void hist_k(const int* __restrict__ dst, int* __restrict__ cnt,
                                              int* __restrict__ rank, int E){
  int e = blockIdx.x*256 + threadIdx.x;
  if (e < E) rank[e] = atomicAdd(&cnt[dst[e]], 1);
}

__global__ __launch_bounds__(256) void blocksum_k(const int* __restrict__ cnt, int* __restrict__ bsum, int N){
  int i = blockIdx.x*256 + threadIdx.x;
  int v = (i < N) ? cnt[i] : 0;
  #pragma unroll
  for (int off = 32; off; off >>= 1) v += __shfl_down(v, off, 64);
  __shared__ int s[4];
  if ((threadIdx.x & 63) == 0) s[threadIdx.x >> 6] = v;
  __syncthreads();
  if (threadIdx.x == 0) bsum[blockIdx.x] = s[0] + s[1] + s[2] + s[3];
}

__global__ __launch_bounds__(512) void scan_small_k(const int* __restrict__ bsum, int* __restrict__ boff, int NB){
  __shared__ int s[512];
  int t = threadIdx.x;
  int v = (t < NB) ? bsum[t] : 0;
  s[t] = v; __syncthreads();
  for (int off = 1; off < 512; off <<= 1){
    int x = (t >= off) ? s[t-off] : 0;
    __syncthreads();
    s[t] += x;
    __syncthreads();
  }
  if (t < NB) boff[t] = s[t] - v;
}

__global__ __launch_bounds__(256) void scan_final_k(const int* __restrict__ cnt, const int* __restrict__ boff,
                                                    int* __restrict__ rowptr,
                                                    float* __restrict__ dinv, int N){
  __shared__ int s[256];
  int t = threadIdx.x;
  int i = blockIdx.x*256 + t;
  int v = (i < N) ? cnt[i] : 0;
  s[t] = v; __syncthreads();
  for (int off = 1; off < 256; off <<= 1){
    int x = (t >= off) ? s[t-off] : 0;
    __syncthreads();
    s[t] += x;
    __syncthreads();
  }
  int excl = s[t] - v + boff[blockIdx.x];
  if (i < N){
    rowptr[i] = excl;
    dinv[i]   = rsqrtf((float)v + 1.0f);
    if (i == N-1) rowptr[N] = excl + v;
  }
}

__global__ __launch_bounds__(256) void fill_k(const int* __restrict__ src, const int* __restrict__ dst,
                                              const int* __restrict__ rowptr, const int* __restrict__ rank,
                                              int* __restrict__ col, int E){
  int e = blockIdx.x*256 + threadIdx.x;
  if (e >= E) return;
  col[rowptr[dst[e]] + rank[e]] = src[e];
}

// ---------------- weight prep: Bt[m][n][k] = (fp16) W_m[k][n] ----------------
// m=0: W_in; m=1..3: W_gnn[i]

__global__ __launch_bounds__(256) void prepw_k(const float* __restrict__ Win, const float* __restrict__ Wgnn,
                                               _Float16* __restrict__ Bt){
  int idx = blockIdx.x*256 + threadIdx.x;     // 4*16384 total
  int m = idx >> 14;
  int r = idx & 16383;
  int k = r >> 7, n = r & 127;
  const float* W = (m == 0) ? Win : (Wgnn + (size_t)(m-1)*16384);
  Bt[(size_t)m*16384 + n*128 + k] = (_Float16)W[k*128 + n];
}

// ---------------- MFMA fp16 GEMM: M x 128 x 128 ----------------
// AF16: A in fp16 (else fp32, cast during staging).
// EPI 0: C = (fp16) relu(A@W + bias)      [input projection]
// EPI 1: C = (fp16) dinv[row] * (A@W)     [layer gemm -> hws]
// 256 threads = 4 waves; each wave computes 32 rows x 128 cols via 16x16x32 MFMA.
// LDS: As/Bs 128x128 fp16, XOR-swizzled (G4): byte ^= (row&7)<<4.

template<int AF16, int EPI>
__global__ __launch_bounds__(256) void mgemm_k(const void* __restrict__ Ap, const _Float16* __restrict__ Bt,
                                               const float* __restrict__ bias, const float* __restrict__ dinv,
                                               _Float16* __restrict__ C, int M){
  __shared__ _Float16 As[128*128];
  __shared__ _Float16 Bs[128*128];
  const int tid = threadIdx.x;
  const int m0 = blockIdx.x * 128;

  // ---- stage B (fp16 pre-transposed: Bt[n][k]) ----
  {
    int n = tid >> 1, kb = (tid & 1) * 64;
    const half8_t* srcb = (const half8_t*)(Bt + n*128 + kb);
    #pragma unroll
    for (int q = 0; q < 8; ++q){
      uint32_t byte = (uint32_t)(n*256 + kb*2 + q*16) ^ (uint32_t)((n & 7) << 4);
      *(half8_t*)((char*)Bs + byte) = srcb[q];
    }
  }
  // ---- stage A ----
  {
    int rr = tid >> 1, kb = (tid & 1) * 64;
    int row = m0 + rr; if (row >= M) row = M - 1;
    if (AF16){
      const half8_t* srca = (const half8_t*)((const _Float16*)Ap + (size_t)row*128 + kb);
      #pragma unroll
      for (int q = 0; q < 8; ++q){
        uint32_t byte = (uint32_t)(rr*256 + kb*2 + q*16) ^ (uint32_t)((rr & 7) << 4);
        *(half8_t*)((char*)As + byte) = srca[q];
      }
    } else {
      const float4* srca = (const float4*)((const float*)Ap + (size_t)row*128 + kb);
      #pragma unroll
      for (int q = 0; q < 8; ++q){
        float4 f0 = srca[2*q], f1 = srca[2*q+1];
        half8_t h;
        h[0]=(_Float16)f0.x; h[1]=(_Float16)f0.y; h[2]=(_Float16)f0.z; h[3]=(_Float16)f0.w;
        h[4]=(_Float16)f1.x; h[5]=(_Float16)f1.y; h[6]=(_Float16)f1.z; h[7]=(_Float16)f1.w;
        uint32_t byte = (uint32_t)(rr*256 + kb*2 + q*16) ^ (uint32_t)((rr & 7) << 4);
        *(half8_t*)((char*)As + byte) = h;
      }
    }
  }
  __syncthreads();

  const int w = tid >> 6, lane = tid & 63;
  const int l15 = lane & 15, lq = lane >> 4;

  f32x4_t acc[2][8];
  #pragma unroll
  for (int rg = 0; rg < 2; ++rg)
    #pragma unroll
    for (int cg = 0; cg < 8; ++cg)
      acc[rg][cg] = (f32x4_t){0.f,0.f,0.f,0.f};

  #pragma unroll
  for (int ks = 0; ks < 4; ++ks){
    half8_t a[2], b[8];
    #pragma unroll
    for (int rg = 0; rg < 2; ++rg){
      int row = w*32 + rg*16 + l15;
      uint32_t byte = (uint32_t)(row*256 + (ks*32 + lq*8)*2) ^ (uint32_t)((row & 7) << 4);
      a[rg] = *(const half8_t*)((const char*)As + byte);
    }
    #pragma unroll
    for (int cg = 0; cg < 8; ++cg){
      int coln = cg*16 + l15;
      uint32_t byte = (uint32_t)(coln*256 + (ks*32 + lq*8)*2) ^ (uint32_t)((coln & 7) << 4);
      b[cg] = *(const half8_t*)((const char*)Bs + byte);
    }
    #pragma unroll
    for (int rg = 0; rg < 2; ++rg)
      #pragma unroll
      for (int cg = 0; cg < 8; ++cg)
        acc[rg][cg] = __builtin_amdgcn_mfma_f32_16x16x32_f16(a[rg], b[cg], acc[rg][cg], 0, 0, 0);
  }

  float bl[8];
  if (EPI == 0){
    #pragma unroll
    for (int cg = 0; cg < 8; ++cg) bl[cg] = bias[cg*16 + l15];
  }

  #pragma unroll
  for (int rg = 0; rg < 2; ++rg){
    #pragma unroll
    for (int r = 0; r < 4; ++r){
      int grow = m0 + w*32 + rg*16 + lq*4 + r;
      if (grow < M){
        if (EPI == 1){
          float di = dinv[grow];
          #pragma unroll
          for (int cg = 0; cg < 8; ++cg)
            C[(size_t)grow*128 + cg*16 + l15] = (_Float16)(di * acc[rg][cg][r]);
        } else {
          #pragma unroll
          for (int cg = 0; cg < 8; ++cg){
            float v = acc[rg][cg][r] + bl[cg];
            C[(size_t)grow*128 + cg*16 + l15] = (_Float16)fmaxf(v, 0.f);
          }
        }
      }
    }
  }
}

// ---------------- GEMM 64x64 fp32 (small head GEMMs) ----------------

template<int ACT>
__global__ __launch_bounds__(256) void gemm_k(const float* __restrict__ A, const float* __restrict__ B,
                                              const float* __restrict__ bias, float* __restrict__ C,
                                              int M, int N, int K){
  __shared__ float As[16][68];
  __shared__ float Bs[16][68];
  int tid = threadIdx.x;
  int m0 = blockIdx.x * 64, n0 = blockIdx.y * 64;
  int ty = tid >> 4, tx = tid & 15;
  int lm = tid >> 2, lkq = tid & 3;
  int lk = tid >> 4, ln4 = tid & 15;
  int arow = m0 + lm; if (arow >= M) arow = M - 1;

  float acc[4][4] = {{0.f}};

  for (int k0 = 0; k0 < K; k0 += 16){
    float4 av = *(const float4*)&A[(size_t)arow*K + k0 + lkq*4];
    float4 bv = *(const float4*)&B[(size_t)(k0+lk)*N + n0 + ln4*4];
    As[lkq*4+0][lm] = av.x; As[lkq*4+1][lm] = av.y; As[lkq*4+2][lm] = av.z; As[lkq*4+3][lm] = av.w;
    *(float4*)&Bs[lk][ln4*4] = bv;
    __syncthreads();
    #pragma unroll
    for (int kk = 0; kk < 16; ++kk){
      const float4 a = *(const float4*)&As[kk][ty*4];
      const float4 b = *(const float4*)&Bs[kk][tx*4];
      acc[0][0] += a.x*b.x; acc[0][1] += a.x*b.y; acc[0][2] += a.x*b.z; acc[0][3] += a.x*b.w;
      acc[1][0] += a.y*b.x; acc[1][1] += a.y*b.y; acc[1][2] += a.y*b.z; acc[1][3] += a.y*b.w;
      acc[2][0] += a.z*b.x; acc[2][1] += a.z*b.y; acc[2][2] += a.z*b.z; acc[2][3] += a.z*b.w;
      acc[3][0] += a.w*b.x; acc[3][1] += a.w*b.y; acc[3][2] += a.w*b.z; acc[3][3] += a.w*b.w;
    }
    __syncthreads();
  }

  float bv0 = 0.f, bv1 = 0.f, bv2 = 0.f, bv3 = 0.f;
  if (bias){
    const float4 b4 = *(const float4*)&bias[n0 + tx*4];
    bv0 = b4.x; bv1 = b4.y; bv2 = b4.z; bv3 = b4.w;
  }
  #pragma unroll
  for (int i = 0; i < 4; ++i){
    int r = m0 + ty*4 + i;
    if (r < M){
      float4 o;
      o.x = acc[i][0] + bv0; o.y = acc[i][1] + bv1; o.z = acc[i][2] + bv2; o.w = acc[i][3] + bv3;
      if (ACT == 1){ o.x = fmaxf(o.x,0.f); o.y = fmaxf(o.y,0.f); o.z = fmaxf(o.z,0.f); o.w = fmaxf(o.w,0.f); }
      *(float4*)&C[(size_t)r*N + n0 + tx*4] = o;
    }
  }
}

// ---------------- GCN aggregation + BN + ReLU ----------------
// hws fp16 (rows pre-scaled by dinv[src]); packed-fp16 partial accumulators
// (each chain sums only ~deg/8 values), fp32 combine; writes h as fp16.

__global__ __launch_bounds__(256) void agg_k(const _Float16* __restrict__ hws, _Float16* __restrict__ hout,
                                             const int* __restrict__ rowptr, const int* __restrict__ col,
                                             const float* __restrict__ dinv,
                                             const float* __restrict__ bgnn, const float* __restrict__ gamma,
                                             const float* __restrict__ beta, const float* __restrict__ mean,
                                             const float* __restrict__ var, int N){
  int n = (blockIdx.x * blockDim.x + threadIdx.x) >> 6;
  if (n >= N) return;
  int lane = threadIdx.x & 63;
  int half = lane >> 5;
  int sl   = lane & 31;
  int f    = sl * 4;
  int beg = rowptr[n], end = rowptr[n+1];

  half4_t H0 = {0,0,0,0}, H1 = {0,0,0,0}, H2 = {0,0,0,0}, H3 = {0,0,0,0};

  int j = beg + half;
  for (; j + 6 < end; j += 8){
    int s0 = col[j], s1 = col[j+2], s2 = col[j+4], s3 = col[j+6];
    H0 += *(const half4_t*)&hws[(size_t)s0*128 + f];
    H1 += *(const half4_t*)&hws[(size_t)s1*128 + f];
    H2 += *(const half4_t*)&hws[(size_t)s2*128 + f];
    H3 += *(const half4_t*)&hws[(size_t)s3*128 + f];
  }
  for (; j < end; j += 2){
    int s0 = col[j];
    H0 += *(const half4_t*)&hws[(size_t)s0*128 + f];
  }

  float4 A0;
  A0.x = (float)H0[0] + (float)H1[0] + (float)H2[0] + (float)H3[0];
  A0.y = (float)H0[1] + (float)H1[1] + (float)H2[1] + (float)H3[1];
  A0.z = (float)H0[2] + (float)H1[2] + (float)H2[2] + (float)H3[2];
  A0.w = (float)H0[3] + (float)H1[3] + (float)H2[3] + (float)H3[3];

  A0.x += __shfl_xor(A0.x, 32, 64);
  A0.y += __shfl_xor(A0.y, 32, 64);
  A0.z += __shfl_xor(A0.z, 32, 64);
  A0.w += __shfl_xor(A0.w, 32, 64);

  if (half == 0){
    float di = dinv[n];
    const half4_t hv = *(const half4_t*)&hws[(size_t)n*128 + f];
    const float4 bg = *(const float4*)&bgnn[f];
    const float4 gm = *(const float4*)&gamma[f];
    const float4 bt = *(const float4*)&beta[f];
    const float4 mn = *(const float4*)&mean[f];
    const float4 vr = *(const float4*)&var[f];
    float o0 = (di*(A0.x + (float)hv[0]) + bg.x - mn.x) * (gm.x * rsqrtf(vr.x + 1e-5f)) + bt.x;
    float o1 = (di*(A0.y + (float)hv[1]) + bg.y - mn.y) * (gm.y * rsqrtf(vr.y + 1e-5f)) + bt.y;
    float o2 = (di*(A0.z + (float)hv[2]) + bg.z - mn.z) * (gm.z * rsqrtf(vr.z + 1e-5f)) + bt.z;
    float o3 = (di*(A0.w + (float)hv[3]) + bg.w - mn.w) * (gm.w * rsqrtf(vr.w + 1e-5f)) + bt.w;
    half4_t o;
    o[0] = (_Float16)fmaxf(o0, 0.f);
    o[1] = (_Float16)fmaxf(o1, 0.f);
    o[2] = (_Float16)fmaxf(o2, 0.f);
    o[3] = (_Float16)fmaxf(o3, 0.f);
    *(half4_t*)&hout[(size_t)n*128 + f] = o;
  }
}

// ---------------- user gather (fp16 h -> fp32 uh), nlp bias, head ----------------

__global__ __launch_bounds__(256) void gather_k(const _Float16* __restrict__ h, const int* __restrict__ uidx,
                                                float* __restrict__ uh, int B){
  int g = blockIdx.x*256 + threadIdx.x;
  if (g >= B*128) return;
  int i = g >> 7, f = g & 127;
  uh[g] = (float)h[(size_t)uidx[i]*128 + f];
}

__global__ __launch_bounds__(256) void initc1_k(const float* __restrict__ b1, float* __restrict__ c1){
  c1[threadIdx.x] = b1[threadIdx.x];
}

__global__ __launch_bounds__(256) void c1acc_k(const float* __restrict__ nlp, const float* __restrict__ W1,
                                               float* __restrict__ c1, int NLP){
  int b = blockIdx.x;
  int c  = (b & 3) * 64 + (threadIdx.x & 63);
  int dq = threadIdx.x >> 6;
  int d0 = (b >> 2) * 99;
  float acc = 0.f;
  for (int d = d0 + dq; d < d0 + 99 && d < NLP; d += 4)
    acc += nlp[d] * W1[(size_t)(64 + d) * 256 + c];
  __shared__ float s[256];
  s[threadIdx.x] = acc; __syncthreads();
  if (dq == 0){
    float t = s[threadIdx.x] + s[threadIdx.x + 64] + s[threadIdx.x + 128] + s[threadIdx.x + 192];
    atomicAdd(&c1[c], t);
  }
}

__global__ __launch_bounds__(256) void head_k(const float* __restrict__ z2, const float* __restrict__ W3,
                                              const float* __restrict__ b3, float* __restrict__ out, int B){
  int gid = blockIdx.x * blockDim.x + threadIdx.x;
  int u = gid >> 6, l = gid & 63;
  if (u >= B) return;
  float v = z2[(size_t)u*128 + l] * W3[l] + z2[(size_t)u*128 + 64 + l] * W3[64 + l];
  #pragma unroll
  for (int off = 32; off; off >>= 1) v += __shfl_down(v, off, 64);
  if (l == 0) out[u] = 1.f / (1.f + expf(-(v + b3[0])));
}

// ---------------- host ----------------

static void launch_gemm(int act, const float* A, const float* Bm, const float* bias, float* C,
                        int M, int N, int K, hipStream_t s){
  dim3 g((M + 63) / 64, N / 64);
  if (act) hipLaunchKernelGGL((gemm_k<1>), g, dim3(256), 0, s, A, Bm, bias, C, M, N, K);
  else     hipLaunchKernelGGL((gemm_k<0>), g, dim3(256), 0, s, A, Bm, bias, C, M, N, K);
}

extern "C" void kernel_launch(void* const* d_in, const int* in_sizes, int n_in,
                              void* d_out, int out_size, void* d_ws, size_t ws_size,
                              hipStream_t stream){
  const float* x     = (const float*)d_in[0];
  const float* nlp   = (const float*)d_in[1];
  const int*   eidx  = (const int*)  d_in[2];
  const int*   uidx  = (const int*)  d_in[3];
  const float* W_in  = (const float*)d_in[4];
  const float* b_in  = (const float*)d_in[5];
  const float* W_gnn = (const float*)d_in[6];
  const float* b_gnn = (const float*)d_in[7];
  const float* gam   = (const float*)d_in[8];
  const float* bet   = (const float*)d_in[9];
  const float* mean  = (const float*)d_in[10];
  const float* var   = (const float*)d_in[11];
  const float* Wproj = (const float*)d_in[12];
  const float* bproj = (const float*)d_in[13];
  const float* W1    = (const float*)d_in[14];
  const float* b1    = (const float*)d_in[15];
  const float* W2    = (const float*)d_in[16];
  const float* b2    = (const float*)d_in[17];
  const float* W3    = (const float*)d_in[18];
  const float* b3    = (const float*)d_in[19];
  float* out = (float*)d_out;

  const int N   = in_sizes[0] / 128;   // 100000
  const int E   = in_sizes[2] / 2;     // 1600000
  const int B   = in_sizes[3];         // 4096
  const int NLP = in_sizes[1];         // 786
  const int HID = 128;

  char* p = (char*)d_ws;
  auto carve = [&](size_t bytes) -> void* {
    void* q = (void*)p;
    p += (bytes + 255) & ~(size_t)255;
    return q;
  };
  int*      cnt    = (int*)     carve((size_t)N * 4);
  int*      rowptr = (int*)     carve((size_t)(N + 1) * 4);
  int*      rank   = (int*)     carve((size_t)E * 4);
  int*      bsum   = (int*)     carve(512 * 4);
  int*      boff   = (int*)     carve(512 * 4);
  float*    dinv   = (float*)   carve((size_t)N * 4);
  int*      col    = (int*)     carve((size_t)E * 4);
  _Float16* Bt     = (_Float16*)carve((size_t)4 * 128 * 128 * 2);
  _Float16* h      = (_Float16*)carve((size_t)N * HID * 2);
  _Float16* hws    = (_Float16*)carve((size_t)N * HID * 2);
  float*    uh     = (float*)   carve((size_t)B * HID * 4);
  float*    embu   = (float*)   carve((size_t)B * 64 * 4);
  float*    z1     = (float*)   carve((size_t)B * 256 * 4);
  float*    z2     = (float*)   carve((size_t)B * 128 * 4);
  float*    c1     = (float*)   carve(256 * 4);

  const int* src = eidx;
  const int* dst = eidx + E;

  const int NB = (N + 255) / 256;   // 391 (<512)
  const int GB = (N + 127) / 128;   // 782 gemm blocks

  // ---- CSR build ----
  hipMemsetAsync(cnt, 0, (size_t)N * 4, stream);
  hipLaunchKernelGGL(hist_k, dim3((E + 255) / 256), dim3(256), 0, stream, dst, cnt, rank, E);
  hipLaunchKernelGGL(blocksum_k, dim3(NB), dim3(256), 0, stream, cnt, bsum, N);
  hipLaunchKernelGGL(scan_small_k, dim3(1), dim3(512), 0, stream, bsum, boff, NB);
  hipLaunchKernelGGL(scan_final_k, dim3(NB), dim3(256), 0, stream, cnt, boff, rowptr, dinv, N);
  hipLaunchKernelGGL(fill_k, dim3((E + 255) / 256), dim3(256), 0, stream, src, dst, rowptr, rank, col, E);

  // ---- weight prep (fp16, transposed) ----
  hipLaunchKernelGGL(prepw_k, dim3(256), dim3(256), 0, stream, W_in, W_gnn, Bt);

  // ---- input projection: h = (fp16) relu(x @ W_in + b_in)  [MFMA] ----
  hipLaunchKernelGGL((mgemm_k<0,0>), dim3(GB), dim3(256), 0, stream,
                     (const void*)x, Bt, b_in, (const float*)nullptr, h, N);

  // ---- 3 GCN layers ----
  for (int i = 0; i < 3; ++i){
    hipLaunchKernelGGL((mgemm_k<1,1>), dim3(GB), dim3(256), 0, stream,
                       (const void*)h, Bt + (size_t)(i+1)*16384, (const float*)nullptr, dinv, hws, N);
    hipLaunchKernelGGL(agg_k, dim3((N * 64 + 255) / 256), dim3(256), 0, stream,
                       hws, h, rowptr, col, dinv,
                       b_gnn + i * 128, gam + i * 128, bet + i * 128, mean + i * 128, var + i * 128, N);
  }

  // ---- user head ----
  hipLaunchKernelGGL(gather_k, dim3((B * 128 + 255) / 256), dim3(256), 0, stream, h, uidx, uh, B);
  hipLaunchKernelGGL(initc1_k, dim3(1), dim3(256), 0, stream, b1, c1);
  hipLaunchKernelGGL(c1acc_k, dim3(32), dim3(256), 0, stream, nlp, W1, c1, NLP);

  launch_gemm(0, uh, Wproj, bproj, embu, B, 64, 128, stream);
  launch_gemm(1, embu, W1, c1, z1, B, 256, 64, stream);
  launch_gemm(1, z1, W2, b2, z2, B, 128, 256, stream);
  hipLaunchKernelGGL(head_k, dim3((B * 64 + 255) / 256), dim3(256), 0, stream, z2, W3, b3, out, B);
}